// Round 1
// baseline (25.547 us; speedup 1.0000x reference)
//
#include <hip/hip_runtime.h>
#include <hip/hip_bf16.h>

// Weighted BCE per-row loss:
//   w   = t*W_POS + (1-t)*W_NEG        (W broadcast over rows)
//   L   = -w * ( t*log(p+eps) + (1-t)*log(1-p+eps) )
//   out = sum_c(L) / sum_c(w)
// N = 2,000,000 rows, C = 8. Pure streaming: 136 MB total traffic.

#define EPS 1e-8f

__global__ __launch_bounds__(256) void densenet_loss_kernel(
        const float4* __restrict__ logits,   // N rows x 2 float4
        const float4* __restrict__ targets,  // N rows x 2 float4
        float* __restrict__ out,
        int n) {
    int row = blockIdx.x * blockDim.x + threadIdx.x;
    if (row >= n) return;

    // two float4 per row per array (8 fp32 columns)
    float4 l0 = logits[2 * row + 0];
    float4 l1 = logits[2 * row + 1];
    float4 t0 = targets[2 * row + 0];
    float4 t1 = targets[2 * row + 1];

    const float l[8] = {l0.x, l0.y, l0.z, l0.w, l1.x, l1.y, l1.z, l1.w};
    const float t[8] = {t0.x, t0.y, t0.z, t0.w, t1.x, t1.y, t1.z, t1.w};
    // competition weights (last column = "overall", weighted 7x)
    const float wneg[8] = {1.f, 1.f, 1.f, 1.f, 1.f, 1.f, 1.f, 7.f};
    const float wpos[8] = {2.f, 2.f, 2.f, 2.f, 2.f, 2.f, 2.f, 14.f};

    float num = 0.f;   // sum of w * (t*log(p) + (1-t)*log(1-p))
    float den = 0.f;   // sum of w
#pragma unroll
    for (int c = 0; c < 8; ++c) {
        float ti = t[c];
        float w  = ti * wpos[c] + (1.f - ti) * wneg[c];
        float lp = __logf(l[c] + EPS);          // log(p + eps)
        float lq = __logf(1.f - l[c] + EPS);    // log(1 - p + eps)
        num += w * (ti * lp + (1.f - ti) * lq);
        den += w;
    }
    out[row] = -num / den;
}

extern "C" void kernel_launch(void* const* d_in, const int* in_sizes, int n_in,
                              void* d_out, int out_size, void* d_ws, size_t ws_size,
                              hipStream_t stream) {
    const float4* logits  = (const float4*)d_in[0];
    const float4* targets = (const float4*)d_in[1];
    float* out = (float*)d_out;

    int n = in_sizes[0] / 8;   // rows
    int block = 256;
    int grid = (n + block - 1) / block;
    densenet_loss_kernel<<<grid, block, 0, stream>>>(logits, targets, out, n);
}

// Round 2
// 25.412 us; speedup vs baseline: 1.0053x; 1.0053x over previous
//
#include <hip/hip_runtime.h>
#include <hip/hip_bf16.h>

// Weighted BCE per-row loss, coalesced layout:
// Each thread owns one float4 (= half a row of 8 columns). Lane j and lane
// j^1 hold the two halves of row j>>1; partial sums combine via shfl_xor(1).
// Loads are 16 B/lane, lane-contiguous -> one fully-utilized transaction per
// 8 lanes, unlike the previous 32 B-stride pattern (half-utilized lines).
//
// Weights: wpos = 2*wneg for every column (wneg = 1,1,1,1,1,1,1,7), and
// targets are binary, so w = base*(1+t) and only one log per element:
//   contribution = w * log( t ? p+eps : 1-p+eps )

#define EPS 1e-8f

__global__ __launch_bounds__(256) void densenet_loss_kernel(
        const float4* __restrict__ logits,   // 2N float4
        const float4* __restrict__ targets,  // 2N float4
        float* __restrict__ out,             // N floats
        int n4) {                            // n4 = 2N
    int j = blockIdx.x * blockDim.x + threadIdx.x;
    if (j >= n4) return;

    float4 l4 = logits[j];
    float4 t4 = targets[j];

    const float lv[4] = {l4.x, l4.y, l4.z, l4.w};
    const float tv[4] = {t4.x, t4.y, t4.z, t4.w};

    const bool hi = (j & 1);   // odd float4 = columns 4..7 (col 7 is "overall", base weight 7)

    float num = 0.f;   // sum of w * log(selected arg)
    float den = 0.f;   // sum of w
#pragma unroll
    for (int k = 0; k < 4; ++k) {
        float base = (hi && k == 3) ? 7.f : 1.f;
        float ti   = tv[k];
        float w    = base * (1.f + ti);                       // t=0 -> base, t=1 -> 2*base
        float arg  = (ti > 0.5f) ? (lv[k] + EPS) : (1.f - lv[k] + EPS);
        num += w * __logf(arg);
        den += w;
    }

    // combine the two half-rows (lanes j and j^1 are in the same wave:
    // block start is 256-aligned, so lane parity == j parity)
    num += __shfl_xor(num, 1);
    den += __shfl_xor(den, 1);

    if (!hi) out[j >> 1] = -num / den;
}

extern "C" void kernel_launch(void* const* d_in, const int* in_sizes, int n_in,
                              void* d_out, int out_size, void* d_ws, size_t ws_size,
                              hipStream_t stream) {
    const float4* logits  = (const float4*)d_in[0];
    const float4* targets = (const float4*)d_in[1];
    float* out = (float*)d_out;

    int n4 = in_sizes[0] / 4;   // number of float4 elements (2 per row)
    int block = 256;
    int grid = (n4 + block - 1) / block;
    densenet_loss_kernel<<<grid, block, 0, stream>>>(logits, targets, out, n4);
}